// Round 2
// 527.519 us; speedup vs baseline: 1.1364x; 1.1364x over previous
//
#include <hip/hip_runtime.h>

typedef unsigned short ushort_t;
typedef __attribute__((ext_vector_type(8))) short short8;
typedef __attribute__((ext_vector_type(4))) float floatx4;
typedef __attribute__((ext_vector_type(4))) unsigned int uint4v;

static __device__ __forceinline__ unsigned short f2bf_rn(float f) {
  return (unsigned short)((__float_as_uint(f) + 0x8000u) >> 16);
}
static __device__ __forceinline__ unsigned int packbf(float a, float b) {
  return ((__float_as_uint(a) + 0x8000u) >> 16) |
         ((__float_as_uint(b) + 0x8000u) & 0xFFFF0000u);
}
// async global->LDS, 16B per lane; LDS dest is wave-uniform (HW adds lane*16)
static __device__ __forceinline__ void gld_lds16(const void* g, void* l) {
  __builtin_amdgcn_global_load_lds(
      (const __attribute__((address_space(1))) unsigned int*)g,
      (__attribute__((address_space(3))) unsigned int*)l, 16, 0, 0);
}

// ---------------------------------------------------------------------------
// k1: transpose+cvt expert_w f32 [E=4][D=4096][O=256] -> WT bf16 [E][O][D]
// ---------------------------------------------------------------------------
__global__ __launch_bounds__(256) void k_transpose(const float* __restrict__ We,
                                                   ushort_t* __restrict__ WT) {
  __shared__ float tile[32][33];
  int t = threadIdx.x, tx = t & 31, ty = t >> 5;
  int d0 = blockIdx.x * 32, o0 = blockIdx.y * 32, e = blockIdx.z;
  const float* src = We + (size_t)e * 4096 * 256;
  ushort_t* dst = WT + (size_t)e * 256 * 4096;
#pragma unroll
  for (int r = 0; r < 4; ++r)
    tile[ty + r * 8][tx] = src[(size_t)(d0 + ty + r * 8) * 256 + (o0 + tx)];
  __syncthreads();
#pragma unroll
  for (int r = 0; r < 4; ++r)
    dst[(size_t)(o0 + ty + r * 8) * 4096 + (d0 + tx)] = f2bf_rn(tile[tx][ty + r * 8]);
}

// ---------------------------------------------------------------------------
// k1b: router weight transpose f32 [4096][4] -> WrT32 [4][4096] f32
// ---------------------------------------------------------------------------
__global__ __launch_bounds__(256) void k_prep_router(const float* __restrict__ Wr,
                                                     float* __restrict__ WrT32) {
  int d = blockIdx.x * 256 + threadIdx.x;  // 16 blocks
  float4 w = *(const float4*)(Wr + (size_t)d * 4);
  WrT32[d] = w.x;
  WrT32[4096 + d] = w.y;
  WrT32[2 * 4096 + d] = w.z;
  WrT32[3 * 4096 + d] = w.w;
}

// ---------------------------------------------------------------------------
// k2 v2: routing (identical math/order to verified version) + V -> bf16 store.
// One wave per token. unroll 4 caps VGPR so 8 blocks/CU can reside.
// ---------------------------------------------------------------------------
__global__ __launch_bounds__(256) void k_routing2(const float* __restrict__ V,
                                                  const float* __restrict__ WrT32,
                                                  float* __restrict__ rw_out,
                                                  float* __restrict__ gates,
                                                  ushort_t* __restrict__ Vh) {
  int w = threadIdx.x >> 6, lane = threadIdx.x & 63;
  int b = blockIdx.x * 4 + w;
  const float* vrow = V + (size_t)b * 4096;
  ushort_t* vhrow = Vh + (size_t)b * 4096;
  float a0 = 0.f, a1 = 0.f, a2 = 0.f, a3 = 0.f;
#pragma unroll 4
  for (int j = 0; j < 16; ++j) {
    int d = j * 256 + lane * 4;
    float4 vv = *(const float4*)(vrow + d);
    float4 w0 = *(const float4*)(WrT32 + d);
    float4 w1 = *(const float4*)(WrT32 + 4096 + d);
    float4 w2 = *(const float4*)(WrT32 + 2 * 4096 + d);
    float4 w3 = *(const float4*)(WrT32 + 3 * 4096 + d);
    a0 += vv.x * w0.x + vv.y * w0.y + vv.z * w0.z + vv.w * w0.w;
    a1 += vv.x * w1.x + vv.y * w1.y + vv.z * w1.z + vv.w * w1.w;
    a2 += vv.x * w2.x + vv.y * w2.y + vv.z * w2.z + vv.w * w2.w;
    a3 += vv.x * w3.x + vv.y * w3.y + vv.z * w3.z + vv.w * w3.w;
    uint2 pk;
    pk.x = packbf(vv.x, vv.y);
    pk.y = packbf(vv.z, vv.w);
    *(uint2*)(vhrow + d) = pk;  // same rounding as old in-GEMM packbf
  }
#pragma unroll
  for (int mask = 1; mask < 64; mask <<= 1) {
    a0 += __shfl_xor(a0, mask, 64);
    a1 += __shfl_xor(a1, mask, 64);
    a2 += __shfl_xor(a2, mask, 64);
    a3 += __shfl_xor(a3, mask, 64);
  }
  float mx = fmaxf(fmaxf(a0, a1), fmaxf(a2, a3));
  float e0 = expf(a0 - mx), e1 = expf(a1 - mx), e2 = expf(a2 - mx), e3 = expf(a3 - mx);
  float s = e0 + e1 + e2 + e3;
  float p[4] = {e0 / s, e1 / s, e2 / s, e3 / s};
  int i1 = 0;
#pragma unroll
  for (int k = 1; k < 4; ++k)
    if (p[k] > p[i1]) i1 = k;  // strict >: first index wins ties (lax.top_k)
  int i2 = (i1 == 0) ? 1 : 0;
#pragma unroll
  for (int k = 0; k < 4; ++k)
    if (k != i1 && p[k] > p[i2]) i2 = k;
  float gs = p[i1] + p[i2];
  if (lane < 4) {
    rw_out[(size_t)b * 4 + lane] = p[lane];
    gates[(size_t)b * 4 + lane] = (lane == i1 || lane == i2) ? (p[lane] / gs) : 0.f;
  }
}

// ---------------------------------------------------------------------------
// k3 v2: fused all-expert GEMM + gated combine, m97 structure.
// 512 thr (8 waves, 4x2 over 128m x 64o, all 4 experts), BK=64, single-buffer
// 48KB LDS, global_load_lds dwordx4 with pre-swizzled global source (XOR
// involution -> LDS image bit-identical to the verified reg-staged kernel).
// Per K-step per block: 48KB staged, 256 MFMAs between two barriers.
// XCD-bijective swizzle: 4 bn-blocks of each bm share one XCD's L2 A-panel.
// ---------------------------------------------------------------------------
#define BM2 128
#define BN2 64
#define BK2 64

__global__ __launch_bounds__(512, 4) void k_gemm2(const ushort_t* __restrict__ Vh,
                                                  const ushort_t* __restrict__ WT,
                                                  const float* __restrict__ gates,
                                                  float* __restrict__ out) {
  const int Kd = 4096;
  int g = blockIdx.x;  // 0..511; HW round-robins consecutive ids across 8 XCDs
  int xcd = g & 7, slot = g >> 3;
  int bm = xcd + ((slot >> 2) << 3);  // bm % 8 == xcd  -> panel stays in one L2
  int bn = slot & 3;
  int m0 = bm * BM2, n0 = bn * BN2;

  __shared__ __align__(16) ushort_t Asm[BM2 * BK2];      // 16 KB
  __shared__ __align__(16) ushort_t Bsm[4 * BN2 * BK2];  // 32 KB

  int t = threadIdx.x;
  int w = t >> 6, lane = t & 63;
  int quad = lane >> 4, mi = lane & 15;
  int wm = (w >> 1) * 32, wn = (w & 1) * 32;

  // ---- staging descriptors: per wave 2 A-instrs + 4 B-instrs (1KB each) ----
  // LDS chunk q <- global chunk with c_global = (q&7) ^ (row&7)  (involution)
  size_t aSrc[2];
  int aDst[2];
#pragma unroll
  for (int s = 0; s < 2; ++s) {
    int q = (w * 2 + s) * 64 + lane;  // 0..1023
    int row = q >> 3, c = (q & 7) ^ (row & 7);
    aSrc[s] = (size_t)(m0 + row) * Kd + c * 8;
    aDst[s] = (w * 2 + s) * 512;  // ushort units; wave-uniform
  }
  size_t bSrc[4];
  int bDst[4];
#pragma unroll
  for (int s = 0; s < 4; ++s) {
    int q = (w * 4 + s) * 64 + lane;  // 0..2047 = e*512 + r*8 + cswz
    int e = q >> 9, r = (q >> 3) & 63, c = (q & 7) ^ (r & 7);
    bSrc[s] = (size_t)e * 256 * Kd + (size_t)(n0 + r) * Kd + c * 8;
    bDst[s] = (w * 4 + s) * 512;
  }

  // ---- fragment LDS offsets (same layout/swizzle as verified kernel) ----
  int aOff[2][2], bOff[2][2];
#pragma unroll
  for (int k32 = 0; k32 < 2; ++k32) {
    int cc = k32 * 4 + quad;
#pragma unroll
    for (int i = 0; i < 2; ++i) {
      int ra = wm + i * 16 + mi;
      aOff[k32][i] = (ra * 8 + (cc ^ (ra & 7))) * 8;
    }
#pragma unroll
    for (int j = 0; j < 2; ++j) {
      int rb = wn + j * 16 + mi;
      bOff[k32][j] = (rb * 8 + (cc ^ (rb & 7))) * 8;
    }
  }

  floatx4 zero = {0.f, 0.f, 0.f, 0.f};
  floatx4 acc[4][2][2];
#pragma unroll
  for (int e = 0; e < 4; ++e)
#pragma unroll
    for (int i = 0; i < 2; ++i)
#pragma unroll
      for (int j = 0; j < 2; ++j) acc[e][i][j] = zero;

  for (int kt = 0; kt < Kd / BK2; ++kt) {
    size_t k0 = (size_t)kt * BK2;
    // ---- stage tile kt (async; syncthreads drains vmcnt before barrier) ----
#pragma unroll
    for (int s = 0; s < 2; ++s) gld_lds16(Vh + aSrc[s] + k0, Asm + aDst[s]);
#pragma unroll
    for (int s = 0; s < 4; ++s) gld_lds16(WT + bSrc[s] + k0, Bsm + bDst[s]);
    __syncthreads();

    // ---- 256 MFMAs/block on tile kt ----
#pragma unroll
    for (int k32 = 0; k32 < 2; ++k32) {
      short8 af[2];
#pragma unroll
      for (int i = 0; i < 2; ++i) af[i] = *(const short8*)(Asm + aOff[k32][i]);
#pragma unroll
      for (int e = 0; e < 4; ++e) {
        short8 bfr[2];
#pragma unroll
        for (int j = 0; j < 2; ++j)
          bfr[j] = *(const short8*)(Bsm + e * (BN2 * BK2) + bOff[k32][j]);
#pragma unroll
        for (int i = 0; i < 2; ++i)
#pragma unroll
          for (int j = 0; j < 2; ++j)
            acc[e][i][j] =
                __builtin_amdgcn_mfma_f32_16x16x32_bf16(af[i], bfr[j], acc[e][i][j], 0, 0, 0);
      }
    }
    __syncthreads();
  }

  // ---- epilogue: gated combine, single f32 store ----
#pragma unroll
  for (int i = 0; i < 2; ++i) {
#pragma unroll
    for (int r = 0; r < 4; ++r) {
      int m = m0 + wm + i * 16 + quad * 4 + r;
      float4 gv = *(const float4*)(gates + (size_t)m * 4);
#pragma unroll
      for (int j = 0; j < 2; ++j) {
        float sv = gv.x * acc[0][i][j][r] + gv.y * acc[1][i][j][r] +
                   gv.z * acc[2][i][j][r] + gv.w * acc[3][i][j][r];
        out[(size_t)m * 256 + n0 + wn + j * 16 + mi] = sv;
      }
    }
  }
}

// ===========================================================================
// Fallback path (verified 598us pipeline) — used only if ws_size is too small
// for the 128MB bf16 copy of V.
// ===========================================================================
__global__ __launch_bounds__(256) void k_routing(const float* __restrict__ V,
                                                 const float* __restrict__ WrT32,
                                                 float* __restrict__ rw_out,
                                                 float* __restrict__ gates) {
  int w = threadIdx.x >> 6, lane = threadIdx.x & 63;
  int b = blockIdx.x * 4 + w;
  const float* vrow = V + (size_t)b * 4096;
  float a0 = 0.f, a1 = 0.f, a2 = 0.f, a3 = 0.f;
#pragma unroll
  for (int j = 0; j < 16; ++j) {
    int d = j * 256 + lane * 4;
    float4 vv = *(const float4*)(vrow + d);
    float4 w0 = *(const float4*)(WrT32 + d);
    float4 w1 = *(const float4*)(WrT32 + 4096 + d);
    float4 w2 = *(const float4*)(WrT32 + 2 * 4096 + d);
    float4 w3 = *(const float4*)(WrT32 + 3 * 4096 + d);
    a0 += vv.x * w0.x + vv.y * w0.y + vv.z * w0.z + vv.w * w0.w;
    a1 += vv.x * w1.x + vv.y * w1.y + vv.z * w1.z + vv.w * w1.w;
    a2 += vv.x * w2.x + vv.y * w2.y + vv.z * w2.z + vv.w * w2.w;
    a3 += vv.x * w3.x + vv.y * w3.y + vv.z * w3.z + vv.w * w3.w;
  }
#pragma unroll
  for (int mask = 1; mask < 64; mask <<= 1) {
    a0 += __shfl_xor(a0, mask, 64);
    a1 += __shfl_xor(a1, mask, 64);
    a2 += __shfl_xor(a2, mask, 64);
    a3 += __shfl_xor(a3, mask, 64);
  }
  float mx = fmaxf(fmaxf(a0, a1), fmaxf(a2, a3));
  float e0 = expf(a0 - mx), e1 = expf(a1 - mx), e2 = expf(a2 - mx), e3 = expf(a3 - mx);
  float s = e0 + e1 + e2 + e3;
  float p[4] = {e0 / s, e1 / s, e2 / s, e3 / s};
  int i1 = 0;
#pragma unroll
  for (int k = 1; k < 4; ++k)
    if (p[k] > p[i1]) i1 = k;
  int i2 = (i1 == 0) ? 1 : 0;
#pragma unroll
  for (int k = 0; k < 4; ++k)
    if (k != i1 && p[k] > p[i2]) i2 = k;
  float gs = p[i1] + p[i2];
  if (lane < 4) {
    rw_out[(size_t)b * 4 + lane] = p[lane];
    gates[(size_t)b * 4 + lane] = (lane == i1 || lane == i2) ? (p[lane] / gs) : 0.f;
  }
}

#define BM 128
#define BN 64
#define BK 64

__global__ __launch_bounds__(256, 2) void k_gemm_moe(const float* __restrict__ V,
                                                     const ushort_t* __restrict__ WT,
                                                     const float* __restrict__ gates,
                                                     float* __restrict__ out) {
  const int Kd = 4096;
  int bn = blockIdx.x;
  int bm = blockIdx.y;
  int m0 = bm * BM, n0 = bn * BN;

  __shared__ __align__(16) ushort_t Asm[BM * BK];
  __shared__ __align__(16) ushort_t Bsm[4 * BN * BK];

  int t = threadIdx.x;
  int w = t >> 6, lane = t & 63;
  int quad = lane >> 4, mi = lane & 15;
  int wm = (w >> 1) * 64, wn = (w & 1) * 32;

  int aG[4], aL[4];
#pragma unroll
  for (int j = 0; j < 4; ++j) {
    int q = j * 256 + t;
    int row = q >> 3, c = q & 7;
    aG[j] = (m0 + row) * Kd + c * 8;
    aL[j] = (row * 8 + (c ^ (row & 7))) * 8;
  }
  int bG[8], bL[8];
#pragma unroll
  for (int j = 0; j < 8; ++j) {
    int q = j * 256 + t;
    int eb = q >> 9, rc = q & 511;
    int r = rc >> 3, c = rc & 7;
    bG[j] = eb * (256 * Kd) + (n0 + r) * Kd + c * 8;
    bL[j] = eb * (BN * BK) + (r * 8 + (c ^ (r & 7))) * 8;
  }

  int aOff[2][4], bOff[2][2];
#pragma unroll
  for (int k32 = 0; k32 < 2; ++k32) {
    int cc = k32 * 4 + quad;
#pragma unroll
    for (int i = 0; i < 4; ++i) {
      int rowa = wm + i * 16 + mi;
      aOff[k32][i] = (rowa * 8 + (cc ^ (rowa & 7))) * 8;
    }
#pragma unroll
    for (int j = 0; j < 2; ++j) {
      int rowb = wn + j * 16 + mi;
      bOff[k32][j] = (rowb * 8 + (cc ^ (rowb & 7))) * 8;
    }
  }

  floatx4 zero = {0.f, 0.f, 0.f, 0.f};
  floatx4 acc[4][4][2];
#pragma unroll
  for (int e = 0; e < 4; ++e)
#pragma unroll
    for (int i = 0; i < 4; ++i)
#pragma unroll
      for (int j = 0; j < 2; ++j) acc[e][i][j] = zero;

  float4 ax[4], ay[4];
  short8 bv[8];
#pragma unroll
  for (int j = 0; j < 4; ++j) {
    const float* ap = V + (size_t)aG[j];
    ax[j] = *(const float4*)ap;
    ay[j] = *(const float4*)(ap + 4);
  }
#pragma unroll
  for (int j = 0; j < 8; ++j) bv[j] = *(const short8*)(WT + (size_t)bG[j]);

  for (int kt = 0; kt < Kd / BK; ++kt) {
#pragma unroll
    for (int j = 0; j < 4; ++j) {
      uint4v uv;
      uv.x = packbf(ax[j].x, ax[j].y);
      uv.y = packbf(ax[j].z, ax[j].w);
      uv.z = packbf(ay[j].x, ay[j].y);
      uv.w = packbf(ay[j].z, ay[j].w);
      *(uint4v*)(Asm + aL[j]) = uv;
    }
#pragma unroll
    for (int j = 0; j < 8; ++j) *(short8*)(Bsm + bL[j]) = bv[j];
    __syncthreads();

    if (kt + 1 < Kd / BK) {
      int k0n = (kt + 1) * BK;
#pragma unroll
      for (int j = 0; j < 4; ++j) {
        const float* ap = V + (size_t)(aG[j] + k0n);
        ax[j] = *(const float4*)ap;
        ay[j] = *(const float4*)(ap + 4);
      }
#pragma unroll
      for (int j = 0; j < 8; ++j) bv[j] = *(const short8*)(WT + (size_t)(bG[j] + k0n));
    }

#pragma unroll
    for (int k32 = 0; k32 < 2; ++k32) {
      short8 af[4];
#pragma unroll
      for (int i = 0; i < 4; ++i) af[i] = *(const short8*)(Asm + aOff[k32][i]);
#pragma unroll
      for (int e = 0; e < 4; ++e) {
        short8 bfr[2];
#pragma unroll
        for (int j = 0; j < 2; ++j)
          bfr[j] = *(const short8*)(Bsm + e * (BN * BK) + bOff[k32][j]);
#pragma unroll
        for (int i = 0; i < 4; ++i)
#pragma unroll
          for (int j = 0; j < 2; ++j)
            acc[e][i][j] =
                __builtin_amdgcn_mfma_f32_16x16x32_bf16(af[i], bfr[j], acc[e][i][j], 0, 0, 0);
      }
    }
    __syncthreads();
  }

#pragma unroll
  for (int i = 0; i < 4; ++i) {
#pragma unroll
    for (int r = 0; r < 4; ++r) {
      int m = m0 + wm + i * 16 + quad * 4 + r;
      float4 gv = *(const float4*)(gates + (size_t)m * 4);
#pragma unroll
      for (int j = 0; j < 2; ++j) {
        float sv = gv.x * acc[0][i][j][r] + gv.y * acc[1][i][j][r] +
                   gv.z * acc[2][i][j][r] + gv.w * acc[3][i][j][r];
        out[(size_t)m * 256 + n0 + wn + j * 16 + mi] = sv;
      }
    }
  }
}

// ---------------------------------------------------------------------------
extern "C" void kernel_launch(void* const* d_in, const int* in_sizes, int n_in,
                              void* d_out, int out_size, void* d_ws, size_t ws_size,
                              hipStream_t stream) {
  const float* V = (const float*)d_in[0];   // [16384][4096] f32
  const float* Wr = (const float*)d_in[1];  // [4096][4] f32
  const float* We = (const float*)d_in[2];  // [4][4096][256] f32

  float* out_moe = (float*)d_out;                 // [16384][256] f32
  float* out_rw = out_moe + (size_t)16384 * 256;  // [16384][4] f32

  char* ws = (char*)d_ws;
  float* gates = (float*)ws;                           // 256 KB
  ushort_t* WT = (ushort_t*)(ws + 262144);             // 8 MB bf16 [4][256][4096]
  float* WrT32 = (float*)(ws + 262144 + 8388608);      // 64 KB f32 [4][4096]
  ushort_t* Vh = (ushort_t*)(ws + 262144 + 8388608 + 65536);  // 128 MB bf16 [16384][4096]
  size_t need = 262144ull + 8388608ull + 65536ull + 16384ull * 4096ull * 2ull;

  k_transpose<<<dim3(128, 8, 4), 256, 0, stream>>>(We, WT);
  k_prep_router<<<dim3(16), 256, 0, stream>>>(Wr, WrT32);

  if (ws_size >= need) {
    k_routing2<<<dim3(4096), 256, 0, stream>>>(V, WrT32, out_rw, gates, Vh);
    k_gemm2<<<dim3(512), 512, 0, stream>>>(Vh, WT, gates, out_moe);
  } else {
    k_routing<<<dim3(4096), 256, 0, stream>>>(V, WrT32, out_rw, gates);
    k_gemm_moe<<<dim3(4, 128), 256, 0, stream>>>(V, WT, gates, out_moe);
  }
}

// Round 3
// 525.495 us; speedup vs baseline: 1.1408x; 1.0039x over previous
//
#include <hip/hip_runtime.h>

typedef unsigned short ushort_t;
typedef __attribute__((ext_vector_type(8))) short short8;
typedef __attribute__((ext_vector_type(4))) float floatx4;
typedef __attribute__((ext_vector_type(4))) unsigned int uint4v;

static __device__ __forceinline__ unsigned short f2bf_rn(float f) {
  return (unsigned short)((__float_as_uint(f) + 0x8000u) >> 16);
}
static __device__ __forceinline__ unsigned int packbf(float a, float b) {
  return ((__float_as_uint(a) + 0x8000u) >> 16) |
         ((__float_as_uint(b) + 0x8000u) & 0xFFFF0000u);
}
// async global->LDS, 16B per lane; LDS dest is wave-uniform (HW adds lane*16)
static __device__ __forceinline__ void gld_lds16(const void* g, void* l) {
  __builtin_amdgcn_global_load_lds(
      (const __attribute__((address_space(1))) unsigned int*)g,
      (__attribute__((address_space(3))) unsigned int*)l, 16, 0, 0);
}

// ---------------------------------------------------------------------------
// k1: transpose+cvt expert_w f32 [E=4][D=4096][O=256] -> WT bf16 [E][O][D]
// ---------------------------------------------------------------------------
__global__ __launch_bounds__(256) void k_transpose(const float* __restrict__ We,
                                                   ushort_t* __restrict__ WT) {
  __shared__ float tile[32][33];
  int t = threadIdx.x, tx = t & 31, ty = t >> 5;
  int d0 = blockIdx.x * 32, o0 = blockIdx.y * 32, e = blockIdx.z;
  const float* src = We + (size_t)e * 4096 * 256;
  ushort_t* dst = WT + (size_t)e * 256 * 4096;
#pragma unroll
  for (int r = 0; r < 4; ++r)
    tile[ty + r * 8][tx] = src[(size_t)(d0 + ty + r * 8) * 256 + (o0 + tx)];
  __syncthreads();
#pragma unroll
  for (int r = 0; r < 4; ++r)
    dst[(size_t)(o0 + ty + r * 8) * 4096 + (d0 + tx)] = f2bf_rn(tile[tx][ty + r * 8]);
}

// ---------------------------------------------------------------------------
// k1b: router weight transpose f32 [4096][4] -> WrT32 [4][4096] f32
// ---------------------------------------------------------------------------
__global__ __launch_bounds__(256) void k_prep_router(const float* __restrict__ Wr,
                                                     float* __restrict__ WrT32) {
  int d = blockIdx.x * 256 + threadIdx.x;  // 16 blocks
  float4 w = *(const float4*)(Wr + (size_t)d * 4);
  WrT32[d] = w.x;
  WrT32[4096 + d] = w.y;
  WrT32[2 * 4096 + d] = w.z;
  WrT32[3 * 4096 + d] = w.w;
}

// ---------------------------------------------------------------------------
// k2 v2: routing (identical math/order to verified version) + V -> bf16 store.
// One wave per token. unroll 4 caps VGPR so 8 blocks/CU can reside.
// ---------------------------------------------------------------------------
__global__ __launch_bounds__(256) void k_routing2(const float* __restrict__ V,
                                                  const float* __restrict__ WrT32,
                                                  float* __restrict__ rw_out,
                                                  float* __restrict__ gates,
                                                  ushort_t* __restrict__ Vh) {
  int w = threadIdx.x >> 6, lane = threadIdx.x & 63;
  int b = blockIdx.x * 4 + w;
  const float* vrow = V + (size_t)b * 4096;
  ushort_t* vhrow = Vh + (size_t)b * 4096;
  float a0 = 0.f, a1 = 0.f, a2 = 0.f, a3 = 0.f;
#pragma unroll 4
  for (int j = 0; j < 16; ++j) {
    int d = j * 256 + lane * 4;
    float4 vv = *(const float4*)(vrow + d);
    float4 w0 = *(const float4*)(WrT32 + d);
    float4 w1 = *(const float4*)(WrT32 + 4096 + d);
    float4 w2 = *(const float4*)(WrT32 + 2 * 4096 + d);
    float4 w3 = *(const float4*)(WrT32 + 3 * 4096 + d);
    a0 += vv.x * w0.x + vv.y * w0.y + vv.z * w0.z + vv.w * w0.w;
    a1 += vv.x * w1.x + vv.y * w1.y + vv.z * w1.z + vv.w * w1.w;
    a2 += vv.x * w2.x + vv.y * w2.y + vv.z * w2.z + vv.w * w2.w;
    a3 += vv.x * w3.x + vv.y * w3.y + vv.z * w3.z + vv.w * w3.w;
    uint2 pk;
    pk.x = packbf(vv.x, vv.y);
    pk.y = packbf(vv.z, vv.w);
    *(uint2*)(vhrow + d) = pk;  // same rounding as old in-GEMM packbf
  }
#pragma unroll
  for (int mask = 1; mask < 64; mask <<= 1) {
    a0 += __shfl_xor(a0, mask, 64);
    a1 += __shfl_xor(a1, mask, 64);
    a2 += __shfl_xor(a2, mask, 64);
    a3 += __shfl_xor(a3, mask, 64);
  }
  float mx = fmaxf(fmaxf(a0, a1), fmaxf(a2, a3));
  float e0 = expf(a0 - mx), e1 = expf(a1 - mx), e2 = expf(a2 - mx), e3 = expf(a3 - mx);
  float s = e0 + e1 + e2 + e3;
  float p[4] = {e0 / s, e1 / s, e2 / s, e3 / s};
  int i1 = 0;
#pragma unroll
  for (int k = 1; k < 4; ++k)
    if (p[k] > p[i1]) i1 = k;  // strict >: first index wins ties (lax.top_k)
  int i2 = (i1 == 0) ? 1 : 0;
#pragma unroll
  for (int k = 0; k < 4; ++k)
    if (k != i1 && p[k] > p[i2]) i2 = k;
  float gs = p[i1] + p[i2];
  if (lane < 4) {
    rw_out[(size_t)b * 4 + lane] = p[lane];
    gates[(size_t)b * 4 + lane] = (lane == i1 || lane == i2) ? (p[lane] / gs) : 0.f;
  }
}

// ---------------------------------------------------------------------------
// k3 v3: fused all-expert GEMM + gated combine.
// Change vs v2: wave layout 4x2 -> 2x4 (wm-groups x wn-groups).
//   LDS read traffic/block/K-step = Atile*nWn + Btile*nWm = 16*4+32*2 = 128KB
//   (was 16*2+32*4 = 160KB); ds_read_b128/thread/K-step 20 -> 16.
//   Per-output accumulation order unchanged -> bit-identical result.
// Per wave: 64m x 16n per expert; acc[4e][4i] floatx4; af[4] reused over e.
// ---------------------------------------------------------------------------
#define BM2 128
#define BN2 64
#define BK2 64

__global__ __launch_bounds__(512, 4) void k_gemm2(const ushort_t* __restrict__ Vh,
                                                  const ushort_t* __restrict__ WT,
                                                  const float* __restrict__ gates,
                                                  float* __restrict__ out) {
  const int Kd = 4096;
  int g = blockIdx.x;  // 0..511; HW round-robins consecutive ids across 8 XCDs
  int xcd = g & 7, slot = g >> 3;
  int bm = xcd + ((slot >> 2) << 3);  // bm % 8 == xcd  -> panel stays in one L2
  int bn = slot & 3;
  int m0 = bm * BM2, n0 = bn * BN2;

  __shared__ __align__(16) ushort_t Asm[BM2 * BK2];      // 16 KB
  __shared__ __align__(16) ushort_t Bsm[4 * BN2 * BK2];  // 32 KB

  int t = threadIdx.x;
  int w = t >> 6, lane = t & 63;
  int quad = lane >> 4, mi = lane & 15;
  int wm = (w >> 2) * 64;   // 2 wm-groups of 64 rows
  int wn = (w & 3) * 16;    // 4 wn-groups of 16 cols

  // ---- staging descriptors: per wave 2 A-instrs + 4 B-instrs (1KB each) ----
  // LDS chunk q <- global chunk with c_global = (q&7) ^ (row&7)  (involution)
  size_t aSrc[2];
  int aDst[2];
#pragma unroll
  for (int s = 0; s < 2; ++s) {
    int q = (w * 2 + s) * 64 + lane;  // 0..1023
    int row = q >> 3, c = (q & 7) ^ (row & 7);
    aSrc[s] = (size_t)(m0 + row) * Kd + c * 8;
    aDst[s] = (w * 2 + s) * 512;  // ushort units; wave-uniform
  }
  size_t bSrc[4];
  int bDst[4];
#pragma unroll
  for (int s = 0; s < 4; ++s) {
    int q = (w * 4 + s) * 64 + lane;  // 0..2047 = e*512 + r*8 + cswz
    int e = q >> 9, r = (q >> 3) & 63, c = (q & 7) ^ (r & 7);
    bSrc[s] = (size_t)e * 256 * Kd + (size_t)(n0 + r) * Kd + c * 8;
    bDst[s] = (w * 4 + s) * 512;
  }

  // ---- fragment LDS offsets (same swizzle formulas as verified kernel) ----
  int aOff[2][4], bOff[2];
#pragma unroll
  for (int k32 = 0; k32 < 2; ++k32) {
    int cc = k32 * 4 + quad;
#pragma unroll
    for (int i = 0; i < 4; ++i) {
      int ra = wm + i * 16 + mi;
      aOff[k32][i] = (ra * 8 + (cc ^ (ra & 7))) * 8;
    }
    int rb = wn + mi;
    bOff[k32] = (rb * 8 + (cc ^ (rb & 7))) * 8;
  }

  floatx4 zero = {0.f, 0.f, 0.f, 0.f};
  floatx4 acc[4][4];  // [expert][i]
#pragma unroll
  for (int e = 0; e < 4; ++e)
#pragma unroll
    for (int i = 0; i < 4; ++i) acc[e][i] = zero;

  for (int kt = 0; kt < Kd / BK2; ++kt) {
    size_t k0 = (size_t)kt * BK2;
    // ---- stage tile kt (async; syncthreads drains vmcnt before barrier) ----
#pragma unroll
    for (int s = 0; s < 2; ++s) gld_lds16(Vh + aSrc[s] + k0, Asm + aDst[s]);
#pragma unroll
    for (int s = 0; s < 4; ++s) gld_lds16(WT + bSrc[s] + k0, Bsm + bDst[s]);
    __syncthreads();

    // ---- 256 MFMAs/block on tile kt (16/thread/k32, 8 ds_read/thread/k32) --
#pragma unroll
    for (int k32 = 0; k32 < 2; ++k32) {
      short8 af[4];
#pragma unroll
      for (int i = 0; i < 4; ++i) af[i] = *(const short8*)(Asm + aOff[k32][i]);
#pragma unroll
      for (int e = 0; e < 4; ++e) {
        short8 bfr = *(const short8*)(Bsm + e * (BN2 * BK2) + bOff[k32]);
#pragma unroll
        for (int i = 0; i < 4; ++i)
          acc[e][i] =
              __builtin_amdgcn_mfma_f32_16x16x32_bf16(af[i], bfr, acc[e][i], 0, 0, 0);
      }
    }
    __syncthreads();
  }

  // ---- epilogue: gated combine, single f32 store ----
#pragma unroll
  for (int i = 0; i < 4; ++i) {
#pragma unroll
    for (int r = 0; r < 4; ++r) {
      int m = m0 + wm + i * 16 + quad * 4 + r;
      float4 gv = *(const float4*)(gates + (size_t)m * 4);
      float sv = gv.x * acc[0][i][r] + gv.y * acc[1][i][r] +
                 gv.z * acc[2][i][r] + gv.w * acc[3][i][r];
      out[(size_t)m * 256 + n0 + wn + mi] = sv;
    }
  }
}

// ===========================================================================
// Fallback path (verified 598us pipeline) — used only if ws_size is too small
// for the 128MB bf16 copy of V.
// ===========================================================================
__global__ __launch_bounds__(256) void k_routing(const float* __restrict__ V,
                                                 const float* __restrict__ WrT32,
                                                 float* __restrict__ rw_out,
                                                 float* __restrict__ gates) {
  int w = threadIdx.x >> 6, lane = threadIdx.x & 63;
  int b = blockIdx.x * 4 + w;
  const float* vrow = V + (size_t)b * 4096;
  float a0 = 0.f, a1 = 0.f, a2 = 0.f, a3 = 0.f;
#pragma unroll
  for (int j = 0; j < 16; ++j) {
    int d = j * 256 + lane * 4;
    float4 vv = *(const float4*)(vrow + d);
    float4 w0 = *(const float4*)(WrT32 + d);
    float4 w1 = *(const float4*)(WrT32 + 4096 + d);
    float4 w2 = *(const float4*)(WrT32 + 2 * 4096 + d);
    float4 w3 = *(const float4*)(WrT32 + 3 * 4096 + d);
    a0 += vv.x * w0.x + vv.y * w0.y + vv.z * w0.z + vv.w * w0.w;
    a1 += vv.x * w1.x + vv.y * w1.y + vv.z * w1.z + vv.w * w1.w;
    a2 += vv.x * w2.x + vv.y * w2.y + vv.z * w2.z + vv.w * w2.w;
    a3 += vv.x * w3.x + vv.y * w3.y + vv.z * w3.z + vv.w * w3.w;
  }
#pragma unroll
  for (int mask = 1; mask < 64; mask <<= 1) {
    a0 += __shfl_xor(a0, mask, 64);
    a1 += __shfl_xor(a1, mask, 64);
    a2 += __shfl_xor(a2, mask, 64);
    a3 += __shfl_xor(a3, mask, 64);
  }
  float mx = fmaxf(fmaxf(a0, a1), fmaxf(a2, a3));
  float e0 = expf(a0 - mx), e1 = expf(a1 - mx), e2 = expf(a2 - mx), e3 = expf(a3 - mx);
  float s = e0 + e1 + e2 + e3;
  float p[4] = {e0 / s, e1 / s, e2 / s, e3 / s};
  int i1 = 0;
#pragma unroll
  for (int k = 1; k < 4; ++k)
    if (p[k] > p[i1]) i1 = k;
  int i2 = (i1 == 0) ? 1 : 0;
#pragma unroll
  for (int k = 0; k < 4; ++k)
    if (k != i1 && p[k] > p[i2]) i2 = k;
  float gs = p[i1] + p[i2];
  if (lane < 4) {
    rw_out[(size_t)b * 4 + lane] = p[lane];
    gates[(size_t)b * 4 + lane] = (lane == i1 || lane == i2) ? (p[lane] / gs) : 0.f;
  }
}

#define BM 128
#define BN 64
#define BK 64

__global__ __launch_bounds__(256, 2) void k_gemm_moe(const float* __restrict__ V,
                                                     const ushort_t* __restrict__ WT,
                                                     const float* __restrict__ gates,
                                                     float* __restrict__ out) {
  const int Kd = 4096;
  int bn = blockIdx.x;
  int bm = blockIdx.y;
  int m0 = bm * BM, n0 = bn * BN;

  __shared__ __align__(16) ushort_t Asm[BM * BK];
  __shared__ __align__(16) ushort_t Bsm[4 * BN * BK];

  int t = threadIdx.x;
  int w = t >> 6, lane = t & 63;
  int quad = lane >> 4, mi = lane & 15;
  int wm = (w >> 1) * 64, wn = (w & 1) * 32;

  int aG[4], aL[4];
#pragma unroll
  for (int j = 0; j < 4; ++j) {
    int q = j * 256 + t;
    int row = q >> 3, c = q & 7;
    aG[j] = (m0 + row) * Kd + c * 8;
    aL[j] = (row * 8 + (c ^ (row & 7))) * 8;
  }
  int bG[8], bL[8];
#pragma unroll
  for (int j = 0; j < 8; ++j) {
    int q = j * 256 + t;
    int eb = q >> 9, rc = q & 511;
    int r = rc >> 3, c = rc & 7;
    bG[j] = eb * (256 * Kd) + (n0 + r) * Kd + c * 8;
    bL[j] = eb * (BN * BK) + (r * 8 + (c ^ (r & 7))) * 8;
  }

  int aOff[2][4], bOff[2][2];
#pragma unroll
  for (int k32 = 0; k32 < 2; ++k32) {
    int cc = k32 * 4 + quad;
#pragma unroll
    for (int i = 0; i < 4; ++i) {
      int rowa = wm + i * 16 + mi;
      aOff[k32][i] = (rowa * 8 + (cc ^ (rowa & 7))) * 8;
    }
#pragma unroll
    for (int j = 0; j < 2; ++j) {
      int rowb = wn + j * 16 + mi;
      bOff[k32][j] = (rowb * 8 + (cc ^ (rowb & 7))) * 8;
    }
  }

  floatx4 zero = {0.f, 0.f, 0.f, 0.f};
  floatx4 acc[4][4][2];
#pragma unroll
  for (int e = 0; e < 4; ++e)
#pragma unroll
    for (int i = 0; i < 4; ++i)
#pragma unroll
      for (int j = 0; j < 2; ++j) acc[e][i][j] = zero;

  float4 ax[4], ay[4];
  short8 bv[8];
#pragma unroll
  for (int j = 0; j < 4; ++j) {
    const float* ap = V + (size_t)aG[j];
    ax[j] = *(const float4*)ap;
    ay[j] = *(const float4*)(ap + 4);
  }
#pragma unroll
  for (int j = 0; j < 8; ++j) bv[j] = *(const short8*)(WT + (size_t)bG[j]);

  for (int kt = 0; kt < Kd / BK; ++kt) {
#pragma unroll
    for (int j = 0; j < 4; ++j) {
      uint4v uv;
      uv.x = packbf(ax[j].x, ax[j].y);
      uv.y = packbf(ax[j].z, ax[j].w);
      uv.z = packbf(ay[j].x, ay[j].y);
      uv.w = packbf(ay[j].z, ay[j].w);
      *(uint4v*)(Asm + aL[j]) = uv;
    }
#pragma unroll
    for (int j = 0; j < 8; ++j) *(short8*)(Bsm + bL[j]) = bv[j];
    __syncthreads();

    if (kt + 1 < Kd / BK) {
      int k0n = (kt + 1) * BK;
#pragma unroll
      for (int j = 0; j < 4; ++j) {
        const float* ap = V + (size_t)(aG[j] + k0n);
        ax[j] = *(const float4*)ap;
        ay[j] = *(const float4*)(ap + 4);
      }
#pragma unroll
      for (int j = 0; j < 8; ++j) bv[j] = *(const short8*)(WT + (size_t)(bG[j] + k0n));
    }

#pragma unroll
    for (int k32 = 0; k32 < 2; ++k32) {
      short8 af[4];
#pragma unroll
      for (int i = 0; i < 4; ++i) af[i] = *(const short8*)(Asm + aOff[k32][i]);
#pragma unroll
      for (int e = 0; e < 4; ++e) {
        short8 bfr[2];
#pragma unroll
        for (int j = 0; j < 2; ++j)
          bfr[j] = *(const short8*)(Bsm + e * (BN * BK) + bOff[k32][j]);
#pragma unroll
        for (int i = 0; i < 4; ++i)
#pragma unroll
          for (int j = 0; j < 2; ++j)
            acc[e][i][j] =
                __builtin_amdgcn_mfma_f32_16x16x32_bf16(af[i], bfr[j], acc[e][i][j], 0, 0, 0);
      }
    }
    __syncthreads();
  }

#pragma unroll
  for (int i = 0; i < 4; ++i) {
#pragma unroll
    for (int r = 0; r < 4; ++r) {
      int m = m0 + wm + i * 16 + quad * 4 + r;
      float4 gv = *(const float4*)(gates + (size_t)m * 4);
#pragma unroll
      for (int j = 0; j < 2; ++j) {
        float sv = gv.x * acc[0][i][j][r] + gv.y * acc[1][i][j][r] +
                   gv.z * acc[2][i][j][r] + gv.w * acc[3][i][j][r];
        out[(size_t)m * 256 + n0 + wn + j * 16 + mi] = sv;
      }
    }
  }
}

// ---------------------------------------------------------------------------
extern "C" void kernel_launch(void* const* d_in, const int* in_sizes, int n_in,
                              void* d_out, int out_size, void* d_ws, size_t ws_size,
                              hipStream_t stream) {
  const float* V = (const float*)d_in[0];   // [16384][4096] f32
  const float* Wr = (const float*)d_in[1];  // [4096][4] f32
  const float* We = (const float*)d_in[2];  // [4][4096][256] f32

  float* out_moe = (float*)d_out;                 // [16384][256] f32
  float* out_rw = out_moe + (size_t)16384 * 256;  // [16384][4] f32

  char* ws = (char*)d_ws;
  float* gates = (float*)ws;                           // 256 KB
  ushort_t* WT = (ushort_t*)(ws + 262144);             // 8 MB bf16 [4][256][4096]
  float* WrT32 = (float*)(ws + 262144 + 8388608);      // 64 KB f32 [4][4096]
  ushort_t* Vh = (ushort_t*)(ws + 262144 + 8388608 + 65536);  // 128 MB bf16 [16384][4096]
  size_t need = 262144ull + 8388608ull + 65536ull + 16384ull * 4096ull * 2ull;

  k_transpose<<<dim3(128, 8, 4), 256, 0, stream>>>(We, WT);
  k_prep_router<<<dim3(16), 256, 0, stream>>>(Wr, WrT32);

  if (ws_size >= need) {
    k_routing2<<<dim3(4096), 256, 0, stream>>>(V, WrT32, out_rw, gates, Vh);
    k_gemm2<<<dim3(512), 512, 0, stream>>>(Vh, WT, gates, out_moe);
  } else {
    k_routing<<<dim3(4096), 256, 0, stream>>>(V, WrT32, out_rw, gates);
    k_gemm_moe<<<dim3(4, 128), 256, 0, stream>>>(V, WT, gates, out_moe);
  }
}